// Round 1
// baseline (1273.893 us; speedup 1.0000x reference)
//
#include <hip/hip_runtime.h>
#include <math.h>

#define N 8192
#define D 64

typedef short bf16x8 __attribute__((ext_vector_type(8)));
typedef float f32x4 __attribute__((ext_vector_type(4)));

__global__ void init_accs(float* accs) {
    if (threadIdx.x < 6) accs[threadIdx.x] = 0.0f;
}

// Convert fp32 -> bf16 (RNE) and compute pre-scaled row norms: 0.5*log2(e)*||row||^2
__global__ __launch_bounds__(256) void convert_norm(
        const float* __restrict__ X, const float* __restrict__ Y,
        const float* __restrict__ Z,
        unsigned short* __restrict__ bmat, float* __restrict__ nscl) {
    int wid  = blockIdx.x * 4 + (threadIdx.x >> 6);   // global wave id = row id
    int lane = threadIdx.x & 63;                       // D == 64: lane == col
    int mat  = wid >> 13;                              // /8192
    int row  = wid & 8191;
    const float* src = (mat == 0) ? X : (mat == 1 ? Y : Z);
    float v = src[row * D + lane];
    // manual RNE float->bf16 (inputs are finite normals; no NaN handling needed)
    unsigned int bits = __builtin_bit_cast(unsigned int, v);
    unsigned short us = (unsigned short)((bits + 0x7FFFu + ((bits >> 16) & 1u)) >> 16);
    float f = __builtin_bit_cast(float, (unsigned int)us << 16);
    bmat[(size_t)mat * (N * D) + row * D + lane] = us;
    float sq = f * f;
    #pragma unroll
    for (int off = 32; off; off >>= 1) sq += __shfl_xor(sq, off);
    if (lane == 0) nscl[mat * N + row] = sq * 0.72134752044448169f; // 0.5*log2(e)
}

// One 64x64 output tile per block for pair blockIdx.y.
// 4 waves in 2x2; each wave owns a 32x32 region = 2x2 MFMA tiles of 16x16.
__global__ __launch_bounds__(256) void gram_kernel(
        const unsigned short* __restrict__ bmat,
        const float* __restrict__ nscl,
        float* __restrict__ accs) {
    const int PA[6] = {0, 2, 0, 0, 1, 1};  // X,Z,X,X,Y,Y
    const int PB[6] = {0, 2, 2, 1, 1, 2};  // X,Z,Z,Y,Y,Z
    int p  = blockIdx.y;
    int bx = blockIdx.x;
    int ti = bx & 127, tj = bx >> 7;

    const unsigned short* A = bmat + (size_t)PA[p] * (N * D);
    const unsigned short* B = bmat + (size_t)PB[p] * (N * D);
    const float* ca = nscl + PA[p] * N;
    const float* cb = nscl + PB[p] * N;

    int w = threadIdx.x >> 6, lane = threadIdx.x & 63;
    int wr = w >> 1, wc = w & 1;
    int rowBase = ti * 64 + wr * 32;
    int colBase = tj * 64 + wc * 32;
    int r = lane & 15, q = lane >> 4;

    // A/B fragments: lane holds (row/col = base + tile*16 + r), k = kc*32 + q*8 .. +7
    bf16x8 afrag[2][2], bfrag[2][2];
    #pragma unroll
    for (int mt = 0; mt < 2; ++mt)
        #pragma unroll
        for (int kc = 0; kc < 2; ++kc)
            afrag[mt][kc] = *reinterpret_cast<const bf16x8*>(
                A + (size_t)(rowBase + mt * 16 + r) * D + kc * 32 + q * 8);
    #pragma unroll
    for (int nt = 0; nt < 2; ++nt)
        #pragma unroll
        for (int kc = 0; kc < 2; ++kc)
            bfrag[nt][kc] = *reinterpret_cast<const bf16x8*>(
                B + (size_t)(colBase + nt * 16 + r) * D + kc * 32 + q * 8);

    f32x4 acc[2][2];
    #pragma unroll
    for (int mt = 0; mt < 2; ++mt)
        #pragma unroll
        for (int nt = 0; nt < 2; ++nt)
            acc[mt][nt] = (f32x4)0.0f;

    #pragma unroll
    for (int kc = 0; kc < 2; ++kc)
        #pragma unroll
        for (int mt = 0; mt < 2; ++mt)
            #pragma unroll
            for (int nt = 0; nt < 2; ++nt)
                acc[mt][nt] = __builtin_amdgcn_mfma_f32_16x16x32_bf16(
                    afrag[mt][kc], bfrag[nt][kc], acc[mt][nt], 0, 0, 0);

    // epilogue: p_ij = exp2( S*log2e - (0.5*log2e*na + 0.5*log2e*nb) )
    float lsum = 0.0f;
    #pragma unroll
    for (int nt = 0; nt < 2; ++nt) {
        float cbv = cb[colBase + nt * 16 + r];          // col = base + r
        #pragma unroll
        for (int mt = 0; mt < 2; ++mt) {
            #pragma unroll
            for (int e = 0; e < 4; ++e) {
                float cav = ca[rowBase + mt * 16 + q * 4 + e];  // row = base + q*4+e
                float t = __builtin_fmaf(acc[mt][nt][e], 1.4426950408889634f,
                                         -(cav + cbv));
                lsum += exp2f(t);
            }
        }
    }

    #pragma unroll
    for (int off = 32; off; off >>= 1) lsum += __shfl_xor(lsum, off);
    __shared__ float wsum[4];
    if (lane == 0) wsum[w] = lsum;
    __syncthreads();
    if (threadIdx.x == 0)
        atomicAdd(&accs[p], wsum[0] + wsum[1] + wsum[2] + wsum[3]);
}

__global__ void finalize_kernel(const float* __restrict__ accs,
                                float* __restrict__ out) {
    // mean = acc / N^2 / sqrt(2*pi*ksize), ksize=2 -> sqrt(4*pi)
    double inv = 1.0 / (8192.0 * 8192.0 * 3.5449077018110318);
    double mxx = accs[0] * inv, mzz = accs[1] * inv, mxz = accs[2] * inv;
    double mxy = accs[3] * inv, myy = accs[4] * inv, myz = accs[5] * inv;
    double r1 = log(3.0 * sqrt(mxx * mzz + 1e-5) / (mxz + 1e-5));
    double r2 = log(3.0 * sqrt(myy * mzz + 1e-5) / (myz + 1e-5));
    double r3 = log(3.0 * sqrt(mxx * myy + 1e-5) / (mxy + 1e-5));
    out[0] = (float)(10.0 * r1 + r2 + 10.0 * r3);
}

extern "C" void kernel_launch(void* const* d_in, const int* in_sizes, int n_in,
                              void* d_out, int out_size, void* d_ws, size_t ws_size,
                              hipStream_t stream) {
    const float* X = (const float*)d_in[0];
    const float* Y = (const float*)d_in[1];
    const float* Z = (const float*)d_in[2];
    char* ws = (char*)d_ws;
    unsigned short* bmat = (unsigned short*)ws;                       // 3*8192*64 bf16 = 3 MB
    float* nscl = (float*)(ws + (size_t)3 * N * D * 2);               // 3*8192 f32
    float* accs = (float*)(ws + (size_t)3 * N * D * 2 + (size_t)3 * N * 4); // 6 f32
    float* out = (float*)d_out;

    hipLaunchKernelGGL(init_accs, dim3(1), dim3(64), 0, stream, accs);
    hipLaunchKernelGGL(convert_norm, dim3(3 * N / 4), dim3(256), 0, stream,
                       X, Y, Z, bmat, nscl);
    hipLaunchKernelGGL(gram_kernel, dim3(128 * 128, 6), dim3(256), 0, stream,
                       bmat, nscl, accs);
    hipLaunchKernelGGL(finalize_kernel, dim3(1), dim3(1), 0, stream, accs, out);
}

// Round 2
// 213.218 us; speedup vs baseline: 5.9746x; 5.9746x over previous
//
#include <hip/hip_runtime.h>
#include <math.h>

#define N 8192
#define D 64

typedef short bf16x8 __attribute__((ext_vector_type(8)));
typedef float f32x4 __attribute__((ext_vector_type(4)));

__global__ void init_accs(float* accs) {
    if (threadIdx.x < 6) accs[threadIdx.x] = 0.0f;
}

// Convert fp32 -> bf16 (RNE) and compute pre-scaled row norms: 0.5*log2(e)*||row||^2
__global__ __launch_bounds__(256) void convert_norm(
        const float* __restrict__ X, const float* __restrict__ Y,
        const float* __restrict__ Z,
        unsigned short* __restrict__ bmat, float* __restrict__ nscl) {
    int wid  = blockIdx.x * 4 + (threadIdx.x >> 6);   // global wave id = row id
    int lane = threadIdx.x & 63;                       // D == 64: lane == col
    int mat  = wid >> 13;                              // /8192
    int row  = wid & 8191;
    const float* src = (mat == 0) ? X : (mat == 1 ? Y : Z);
    float v = src[row * D + lane];
    unsigned int bits = __builtin_bit_cast(unsigned int, v);
    unsigned short us = (unsigned short)((bits + 0x7FFFu + ((bits >> 16) & 1u)) >> 16);
    float f = __builtin_bit_cast(float, (unsigned int)us << 16);
    bmat[(size_t)mat * (N * D) + row * D + lane] = us;
    float sq = f * f;
    #pragma unroll
    for (int off = 32; off; off >>= 1) sq += __shfl_xor(sq, off);
    if (lane == 0) nscl[mat * N + row] = sq * 0.72134752044448169f; // 0.5*log2(e)
}

// Each block: 64 rows x 2048 cols of one Gram pair. 4 waves in 2x2; each wave
// owns 32 rows x 32 cols per j-iteration, looping 32 j-tiles with B-prefetch.
__global__ __launch_bounds__(256) void gram_kernel(
        const unsigned short* __restrict__ bmat,
        const float* __restrict__ nscl,
        float* __restrict__ accs) {
    const int PA[6] = {0, 2, 0, 0, 1, 1};  // X,Z,X,X,Y,Y
    const int PB[6] = {0, 2, 2, 1, 1, 2};  // X,Z,Z,Y,Y,Z
    int p  = blockIdx.y;
    int bx = blockIdx.x;          // 0..511
    int ti = bx & 127;            // row tile (64 rows)
    int tc = bx >> 7;             // col chunk (2048 cols)

    const unsigned short* A = bmat + (size_t)PA[p] * (N * D);
    const unsigned short* B = bmat + (size_t)PB[p] * (N * D);
    const float* ca = nscl + PA[p] * N;
    const float* cb = nscl + PB[p] * N;

    int w = threadIdx.x >> 6, lane = threadIdx.x & 63;
    int wr = w >> 1, wc = w & 1;
    int rowBase  = ti * 64 + wr * 32;
    int colChunk = tc * 2048 + wc * 32;
    int r = lane & 15, q = lane >> 4;

    // Loop-invariant A fragments and row-norm constants
    bf16x8 afrag[2][2];
    #pragma unroll
    for (int mt = 0; mt < 2; ++mt)
        #pragma unroll
        for (int kc = 0; kc < 2; ++kc)
            afrag[mt][kc] = *reinterpret_cast<const bf16x8*>(
                A + (size_t)(rowBase + mt * 16 + r) * D + kc * 32 + q * 8);
    float cam[2][4];
    #pragma unroll
    for (int mt = 0; mt < 2; ++mt)
        #pragma unroll
        for (int e = 0; e < 4; ++e)
            cam[mt][e] = ca[rowBase + mt * 16 + q * 4 + e];

    bf16x8 bfrag[2][2], bnext[2][2];
    float cbv[2], cbn[2];

    #pragma unroll
    for (int nt = 0; nt < 2; ++nt) {
        #pragma unroll
        for (int kc = 0; kc < 2; ++kc)
            bfrag[nt][kc] = *reinterpret_cast<const bf16x8*>(
                B + (size_t)(colChunk + nt * 16 + r) * D + kc * 32 + q * 8);
        cbv[nt] = cb[colChunk + nt * 16 + r];
    }

    f32x4 lsumv = (f32x4)0.0f;

    #pragma unroll 2
    for (int j = 0; j < 32; ++j) {
        // prefetch next B tile (independent of this iteration's compute)
        if (j < 31) {
            int colN = colChunk + (j + 1) * 64;
            #pragma unroll
            for (int nt = 0; nt < 2; ++nt) {
                #pragma unroll
                for (int kc = 0; kc < 2; ++kc)
                    bnext[nt][kc] = *reinterpret_cast<const bf16x8*>(
                        B + (size_t)(colN + nt * 16 + r) * D + kc * 32 + q * 8);
                cbn[nt] = cb[colN + nt * 16 + r];
            }
        }

        f32x4 acc[2][2];
        #pragma unroll
        for (int mt = 0; mt < 2; ++mt)
            #pragma unroll
            for (int nt = 0; nt < 2; ++nt)
                acc[mt][nt] = (f32x4)0.0f;
        #pragma unroll
        for (int kc = 0; kc < 2; ++kc)
            #pragma unroll
            for (int mt = 0; mt < 2; ++mt)
                #pragma unroll
                for (int nt = 0; nt < 2; ++nt)
                    acc[mt][nt] = __builtin_amdgcn_mfma_f32_16x16x32_bf16(
                        afrag[mt][kc], bfrag[nt][kc], acc[mt][nt], 0, 0, 0);

        // p_ij = exp2( S*log2e - (0.5*log2e*na + 0.5*log2e*nb) )
        #pragma unroll
        for (int nt = 0; nt < 2; ++nt) {
            #pragma unroll
            for (int mt = 0; mt < 2; ++mt) {
                #pragma unroll
                for (int e = 0; e < 4; ++e) {
                    float t = __builtin_fmaf(acc[mt][nt][e], 1.4426950408889634f,
                                             -(cam[mt][e] + cbv[nt]));
                    lsumv[e] += __builtin_amdgcn_exp2f(t);
                }
            }
        }

        #pragma unroll
        for (int nt = 0; nt < 2; ++nt) {
            #pragma unroll
            for (int kc = 0; kc < 2; ++kc)
                bfrag[nt][kc] = bnext[nt][kc];
            cbv[nt] = cbn[nt];
        }
    }

    float lsum = lsumv[0] + lsumv[1] + lsumv[2] + lsumv[3];
    #pragma unroll
    for (int off = 32; off; off >>= 1) lsum += __shfl_xor(lsum, off);
    __shared__ float wsum[4];
    if (lane == 0) wsum[w] = lsum;
    __syncthreads();
    if (threadIdx.x == 0)
        atomicAdd(&accs[p], wsum[0] + wsum[1] + wsum[2] + wsum[3]);
}

__global__ void finalize_kernel(const float* __restrict__ accs,
                                float* __restrict__ out) {
    // mean = acc / N^2 / sqrt(2*pi*ksize), ksize=2 -> sqrt(4*pi)
    double inv = 1.0 / (8192.0 * 8192.0 * 3.5449077018110318);
    double mxx = accs[0] * inv, mzz = accs[1] * inv, mxz = accs[2] * inv;
    double mxy = accs[3] * inv, myy = accs[4] * inv, myz = accs[5] * inv;
    double r1 = log(3.0 * sqrt(mxx * mzz + 1e-5) / (mxz + 1e-5));
    double r2 = log(3.0 * sqrt(myy * mzz + 1e-5) / (myz + 1e-5));
    double r3 = log(3.0 * sqrt(mxx * myy + 1e-5) / (mxy + 1e-5));
    out[0] = (float)(10.0 * r1 + r2 + 10.0 * r3);
}

extern "C" void kernel_launch(void* const* d_in, const int* in_sizes, int n_in,
                              void* d_out, int out_size, void* d_ws, size_t ws_size,
                              hipStream_t stream) {
    const float* X = (const float*)d_in[0];
    const float* Y = (const float*)d_in[1];
    const float* Z = (const float*)d_in[2];
    char* ws = (char*)d_ws;
    unsigned short* bmat = (unsigned short*)ws;                       // 3*8192*64 bf16 = 3 MB
    float* nscl = (float*)(ws + (size_t)3 * N * D * 2);               // 3*8192 f32
    float* accs = (float*)(ws + (size_t)3 * N * D * 2 + (size_t)3 * N * 4); // 6 f32
    float* out = (float*)d_out;

    hipLaunchKernelGGL(init_accs, dim3(1), dim3(64), 0, stream, accs);
    hipLaunchKernelGGL(convert_norm, dim3(3 * N / 4), dim3(256), 0, stream,
                       X, Y, Z, bmat, nscl);
    hipLaunchKernelGGL(gram_kernel, dim3(512, 6), dim3(256), 0, stream,
                       bmat, nscl, accs);
    hipLaunchKernelGGL(finalize_kernel, dim3(1), dim3(1), 0, stream, accs, out);
}

// Round 3
// 195.447 us; speedup vs baseline: 6.5178x; 1.0909x over previous
//
#include <hip/hip_runtime.h>
#include <math.h>

#define N 8192
#define D 64

typedef short bf16x8 __attribute__((ext_vector_type(8)));
typedef float f32x4 __attribute__((ext_vector_type(4)));

__global__ void init_accs(float* accs) {
    if (threadIdx.x < 6) accs[threadIdx.x] = 0.0f;
}

// Convert fp32 -> bf16 of (sqrt(log2e)*x), and row norms pre-scaled so that
// nscl[i] = 0.5 * sum(bf16(s*x)^2) = log2e * ||x||^2 / 2   (s = sqrt(log2e)).
// Then MFMA on scaled inputs gives log2e*(a.b), and
// exp(-(na+nb-2ab)/2) = exp2( log2e*ab - nscl_a - nscl_b ).
__global__ __launch_bounds__(256) void convert_norm(
        const float* __restrict__ X, const float* __restrict__ Y,
        const float* __restrict__ Z,
        unsigned short* __restrict__ bmat, float* __restrict__ nscl) {
    int wid  = blockIdx.x * 4 + (threadIdx.x >> 6);   // global wave id = row id
    int lane = threadIdx.x & 63;                       // D == 64: lane == col
    int mat  = wid >> 13;                              // /8192
    int row  = wid & 8191;
    const float* src = (mat == 0) ? X : (mat == 1 ? Y : Z);
    float v = src[row * D + lane] * 1.2011224087864498f;  // sqrt(log2(e))
    unsigned int bits = __builtin_bit_cast(unsigned int, v);
    unsigned short us = (unsigned short)((bits + 0x7FFFu + ((bits >> 16) & 1u)) >> 16);
    float f = __builtin_bit_cast(float, (unsigned int)us << 16);
    bmat[(size_t)mat * (N * D) + row * D + lane] = us;
    float sq = f * f;
    #pragma unroll
    for (int off = 32; off; off >>= 1) sq += __shfl_xor(sq, off);
    if (lane == 0) nscl[mat * N + row] = sq * 0.5f;
}

// Each block: 64 rows x 4096 cols of one Gram pair (64 j-iterations of 64 cols).
// 4 waves in 2x2; each wave owns 32 rows x 32 cols per j-iteration.
// Norm bias is folded into the MFMA C-operand init; epilogue = exp2 + add.
__global__ __launch_bounds__(256) void gram_kernel(
        const unsigned short* __restrict__ bmat,
        const float* __restrict__ nscl,
        float* __restrict__ accs) {
    const int PA[6] = {0, 2, 0, 0, 1, 1};  // X,Z,X,X,Y,Y
    const int PB[6] = {0, 2, 2, 1, 1, 2};  // X,Z,Z,Y,Y,Z
    int p  = blockIdx.y;
    int bx = blockIdx.x;          // 0..255
    int ti = bx >> 1;             // row strip (64 rows)
    int tc = bx & 1;              // col chunk (4096 cols)

    const unsigned short* A = bmat + (size_t)PA[p] * (N * D);
    const unsigned short* B = bmat + (size_t)PB[p] * (N * D);
    const float* ca = nscl + PA[p] * N;
    const float* cb = nscl + PB[p] * N;

    int w = threadIdx.x >> 6, lane = threadIdx.x & 63;
    int wr = w >> 1, wc = w & 1;
    int rowBase  = ti * 64 + wr * 32;
    int colChunk = tc * 4096 + wc * 32;
    int r = lane & 15, q = lane >> 4;

    // Loop-invariant A fragments and negated row-norm constants
    bf16x8 afrag[2][2];
    #pragma unroll
    for (int mt = 0; mt < 2; ++mt)
        #pragma unroll
        for (int kc = 0; kc < 2; ++kc)
            afrag[mt][kc] = *reinterpret_cast<const bf16x8*>(
                A + (size_t)(rowBase + mt * 16 + r) * D + kc * 32 + q * 8);
    f32x4 ncam[2];
    #pragma unroll
    for (int mt = 0; mt < 2; ++mt)
        #pragma unroll
        for (int e = 0; e < 4; ++e)
            ncam[mt][e] = -ca[rowBase + mt * 16 + q * 4 + e];

    // Per-lane strength-reduced pointers for B fragments / col norms
    const unsigned short* bp = B + (size_t)(colChunk + r) * D + q * 8;
    const float* cbp = cb + colChunk + r;

    f32x4 lsum = (f32x4)0.0f;

    #pragma unroll 2
    for (int j = 0; j < 64; ++j) {
        bf16x8 bfrag[2][2];
        #pragma unroll
        for (int nt = 0; nt < 2; ++nt)
            #pragma unroll
            for (int kc = 0; kc < 2; ++kc)
                bfrag[nt][kc] = *reinterpret_cast<const bf16x8*>(
                    bp + nt * 16 * D + kc * 32);
        float cb0 = cbp[0], cb1 = cbp[16];

        // C-init carries the norm bias: acc = -(na + nb)
        f32x4 acc[2][2];
        #pragma unroll
        for (int mt = 0; mt < 2; ++mt) {
            acc[mt][0] = ncam[mt] - cb0;
            acc[mt][1] = ncam[mt] - cb1;
        }
        #pragma unroll
        for (int kc = 0; kc < 2; ++kc)
            #pragma unroll
            for (int mt = 0; mt < 2; ++mt)
                #pragma unroll
                for (int nt = 0; nt < 2; ++nt)
                    acc[mt][nt] = __builtin_amdgcn_mfma_f32_16x16x32_bf16(
                        afrag[mt][kc], bfrag[nt][kc], acc[mt][nt], 0, 0, 0);

        // epilogue: lsum += exp2(acc)   (acc already = log2e*(ab - na/2 - nb/2))
        #pragma unroll
        for (int mt = 0; mt < 2; ++mt) {
            #pragma unroll
            for (int nt = 0; nt < 2; ++nt) {
                f32x4 ex;
                #pragma unroll
                for (int e = 0; e < 4; ++e)
                    ex[e] = __builtin_amdgcn_exp2f(acc[mt][nt][e]);
                lsum += ex;
            }
        }

        bp  += 64 * D;
        cbp += 64;
    }

    float ls = lsum[0] + lsum[1] + lsum[2] + lsum[3];
    #pragma unroll
    for (int off = 32; off; off >>= 1) ls += __shfl_xor(ls, off);
    __shared__ float wsum[4];
    if (lane == 0) wsum[w] = ls;
    __syncthreads();
    if (threadIdx.x == 0)
        atomicAdd(&accs[p], wsum[0] + wsum[1] + wsum[2] + wsum[3]);
}

__global__ void finalize_kernel(const float* __restrict__ accs,
                                float* __restrict__ out) {
    // mean = acc / N^2 / sqrt(2*pi*ksize), ksize=2 -> sqrt(4*pi)
    double inv = 1.0 / (8192.0 * 8192.0 * 3.5449077018110318);
    double mxx = accs[0] * inv, mzz = accs[1] * inv, mxz = accs[2] * inv;
    double mxy = accs[3] * inv, myy = accs[4] * inv, myz = accs[5] * inv;
    double r1 = log(3.0 * sqrt(mxx * mzz + 1e-5) / (mxz + 1e-5));
    double r2 = log(3.0 * sqrt(myy * mzz + 1e-5) / (myz + 1e-5));
    double r3 = log(3.0 * sqrt(mxx * myy + 1e-5) / (mxy + 1e-5));
    out[0] = (float)(10.0 * r1 + r2 + 10.0 * r3);
}

extern "C" void kernel_launch(void* const* d_in, const int* in_sizes, int n_in,
                              void* d_out, int out_size, void* d_ws, size_t ws_size,
                              hipStream_t stream) {
    const float* X = (const float*)d_in[0];
    const float* Y = (const float*)d_in[1];
    const float* Z = (const float*)d_in[2];
    char* ws = (char*)d_ws;
    unsigned short* bmat = (unsigned short*)ws;                       // 3*8192*64 bf16 = 3 MB
    float* nscl = (float*)(ws + (size_t)3 * N * D * 2);               // 3*8192 f32
    float* accs = (float*)(ws + (size_t)3 * N * D * 2 + (size_t)3 * N * 4); // 6 f32
    float* out = (float*)d_out;

    hipLaunchKernelGGL(init_accs, dim3(1), dim3(64), 0, stream, accs);
    hipLaunchKernelGGL(convert_norm, dim3(3 * N / 4), dim3(256), 0, stream,
                       X, Y, Z, bmat, nscl);
    hipLaunchKernelGGL(gram_kernel, dim3(256, 6), dim3(256), 0, stream,
                       bmat, nscl, accs);
    hipLaunchKernelGGL(finalize_kernel, dim3(1), dim3(1), 0, stream, accs, out);
}

// Round 4
// 94.978 us; speedup vs baseline: 13.4125x; 2.0578x over previous
//
#include <hip/hip_runtime.h>
#include <math.h>

#define N 8192
#define D 64

typedef short bf16x8 __attribute__((ext_vector_type(8)));
typedef float f32x4 __attribute__((ext_vector_type(4)));

__device__ __forceinline__ void gload_lds16(const void* g, void* l) {
    __builtin_amdgcn_global_load_lds(
        (const __attribute__((address_space(1))) void*)g,
        (__attribute__((address_space(3))) void*)l, 16, 0, 0);
}

__global__ void init_accs(float* accs) {
    if (threadIdx.x < 6) accs[threadIdx.x] = 0.0f;
}

// Convert fp32 -> bf16 of (sqrt(log2e)*x); nscl[i] = 0.5*||bf16(s*x)||^2 = log2e*||x||^2/2.
// MFMA on scaled inputs gives log2e*(a.b); exp(-(na+nb-2ab)/2) = exp2(ab' - na' - nb').
__global__ __launch_bounds__(256) void convert_norm(
        const float* __restrict__ X, const float* __restrict__ Y,
        const float* __restrict__ Z,
        unsigned short* __restrict__ bmat, float* __restrict__ nscl) {
    int wid  = blockIdx.x * 4 + (threadIdx.x >> 6);
    int lane = threadIdx.x & 63;
    int mat  = wid >> 13;
    int row  = wid & 8191;
    const float* src = (mat == 0) ? X : (mat == 1 ? Y : Z);
    float v = src[row * D + lane] * 1.2011224087864498f;  // sqrt(log2(e))
    unsigned int bits = __builtin_bit_cast(unsigned int, v);
    unsigned short us = (unsigned short)((bits + 0x7FFFu + ((bits >> 16) & 1u)) >> 16);
    float f = __builtin_bit_cast(float, (unsigned int)us << 16);
    bmat[(size_t)mat * (N * D) + row * D + lane] = us;
    float sq = f * f;
    #pragma unroll
    for (int off = 32; off; off >>= 1) sq += __shfl_xor(sq, off);
    if (lane == 0) nscl[mat * N + row] = sq * 0.5f;
}

// Block: 64 rows x 4096 cols of one pair; 64 iters of 64 cols.
// B staged via global_load_lds into double-buffered LDS with XOR swizzle
// (linear LDS dest + inverse-swizzled global source; swizzled ds_read).
__global__ __launch_bounds__(256, 6) void gram_kernel(
        const unsigned short* __restrict__ bmat,
        const float* __restrict__ nscl,
        float* __restrict__ accs) {
    const int PA[6] = {0, 2, 0, 0, 1, 1};  // X,Z,X,X,Y,Y
    const int PB[6] = {0, 2, 2, 1, 1, 2};  // X,Z,Z,Y,Y,Z
    int p  = blockIdx.y;
    int bx = blockIdx.x;          // 0..255
    int ti = bx >> 1;             // row strip (64 rows)
    int tc = bx & 1;              // col half (4096 cols)

    const unsigned short* A = bmat + (size_t)PA[p] * (N * D);
    const unsigned short* B = bmat + (size_t)PB[p] * (N * D);
    const float* ca = nscl + PA[p] * N;
    const float* cb = nscl + PB[p] * N;

    int tid = threadIdx.x;
    int w = tid >> 6, lane = tid & 63;
    int wr = w >> 1, wc = w & 1;
    int rowBase = ti * 64 + wr * 32;
    int r = lane & 15, q = lane >> 4, r7 = lane & 7;

    __shared__ __align__(128) char lds[2][8192];
    __shared__ float wsum[4];

    // Staging geometry: tile = 64 cols x 128 B, contiguous 8 KB in global.
    // LDS-linear granule g (16B): c = g>>3, slot = g&7 holds logical slot^(c&7).
    int sub = w * 2048;                               // this wave's 2x1KB region
    int l3 = lane >> 3, l7 = lane & 7;
    int laneoff = l3 * 128 + ((l7 ^ l3) << 4);        // inverse-swizzled source
    const char* gB = (const char*)(B + (size_t)(tc * 4096) * D);

    // ds_read fragment offsets: phys = wc*4096 + nt*2048 + r*128 + ((kc*4+q)^r7)*16
    int off0 = wc * 4096 + r * 128 + (((q) ^ r7) << 4);        // kc=0
    int off1 = wc * 4096 + r * 128 + (((4 + q) ^ r7) << 4);    // kc=1

    // Prologue: stage tile 0 into buf 0
    {
        const char* g = gB + sub + laneoff;
        gload_lds16(g,        (void*)&lds[0][sub]);
        gload_lds16(g + 1024, (void*)&lds[0][sub + 1024]);
    }

    // Loop-invariant A fragments and negated row-norm constants
    bf16x8 afrag[2][2];
    #pragma unroll
    for (int mt = 0; mt < 2; ++mt)
        #pragma unroll
        for (int kc = 0; kc < 2; ++kc)
            afrag[mt][kc] = *reinterpret_cast<const bf16x8*>(
                A + (size_t)(rowBase + mt * 16 + r) * D + kc * 32 + q * 8);
    f32x4 ncam[2];
    #pragma unroll
    for (int mt = 0; mt < 2; ++mt)
        #pragma unroll
        for (int e = 0; e < 4; ++e)
            ncam[mt][e] = -ca[rowBase + mt * 16 + q * 4 + e];

    const float* cbp = cb + tc * 4096 + wc * 32 + r;

    asm volatile("s_waitcnt vmcnt(0)" ::: "memory");
    __syncthreads();

    f32x4 lsum = (f32x4)0.0f;

    for (int t = 0; t < 64; ++t) {
        int buf = t & 1;
        // stage next tile into the other buffer (its readers finished last iter)
        if (t < 63) {
            const char* g = gB + (t + 1) * 8192 + sub + laneoff;
            gload_lds16(g,        (void*)&lds[buf ^ 1][sub]);
            gload_lds16(g + 1024, (void*)&lds[buf ^ 1][sub + 1024]);
        }
        float cb0 = cbp[0], cb1 = cbp[16];

        bf16x8 bfrag[2][2];
        bfrag[0][0] = *reinterpret_cast<const bf16x8*>(&lds[buf][off0]);
        bfrag[0][1] = *reinterpret_cast<const bf16x8*>(&lds[buf][off1]);
        bfrag[1][0] = *reinterpret_cast<const bf16x8*>(&lds[buf][off0 + 2048]);
        bfrag[1][1] = *reinterpret_cast<const bf16x8*>(&lds[buf][off1 + 2048]);

        // C-init carries the norm bias: acc = -(na + nb)
        f32x4 acc[2][2];
        acc[0][0] = ncam[0] - cb0; acc[0][1] = ncam[0] - cb1;
        acc[1][0] = ncam[1] - cb0; acc[1][1] = ncam[1] - cb1;

        #pragma unroll
        for (int kc = 0; kc < 2; ++kc)
            #pragma unroll
            for (int mt = 0; mt < 2; ++mt)
                #pragma unroll
                for (int nt = 0; nt < 2; ++nt)
                    acc[mt][nt] = __builtin_amdgcn_mfma_f32_16x16x32_bf16(
                        afrag[mt][kc], bfrag[nt][kc], acc[mt][nt], 0, 0, 0);

        #pragma unroll
        for (int mt = 0; mt < 2; ++mt) {
            #pragma unroll
            for (int nt = 0; nt < 2; ++nt) {
                f32x4 ex;
                #pragma unroll
                for (int e = 0; e < 4; ++e)
                    ex[e] = __builtin_amdgcn_exp2f(acc[mt][nt][e]);
                lsum += ex;
            }
        }

        cbp += 64;
        asm volatile("s_waitcnt vmcnt(0)" ::: "memory");
        __syncthreads();
    }

    float ls = lsum[0] + lsum[1] + lsum[2] + lsum[3];
    #pragma unroll
    for (int off = 32; off; off >>= 1) ls += __shfl_xor(ls, off);
    if (lane == 0) wsum[w] = ls;
    __syncthreads();
    if (tid == 0)
        atomicAdd(&accs[p], wsum[0] + wsum[1] + wsum[2] + wsum[3]);
}

__global__ void finalize_kernel(const float* __restrict__ accs,
                                float* __restrict__ out) {
    double inv = 1.0 / (8192.0 * 8192.0 * 3.5449077018110318);
    double mxx = accs[0] * inv, mzz = accs[1] * inv, mxz = accs[2] * inv;
    double mxy = accs[3] * inv, myy = accs[4] * inv, myz = accs[5] * inv;
    double r1 = log(3.0 * sqrt(mxx * mzz + 1e-5) / (mxz + 1e-5));
    double r2 = log(3.0 * sqrt(myy * mzz + 1e-5) / (myz + 1e-5));
    double r3 = log(3.0 * sqrt(mxx * myy + 1e-5) / (mxy + 1e-5));
    out[0] = (float)(10.0 * r1 + r2 + 10.0 * r3);
}

extern "C" void kernel_launch(void* const* d_in, const int* in_sizes, int n_in,
                              void* d_out, int out_size, void* d_ws, size_t ws_size,
                              hipStream_t stream) {
    const float* X = (const float*)d_in[0];
    const float* Y = (const float*)d_in[1];
    const float* Z = (const float*)d_in[2];
    char* ws = (char*)d_ws;
    unsigned short* bmat = (unsigned short*)ws;                       // 3 MB
    float* nscl = (float*)(ws + (size_t)3 * N * D * 2);               // 3*8192 f32
    float* accs = (float*)(ws + (size_t)3 * N * D * 2 + (size_t)3 * N * 4);
    float* out = (float*)d_out;

    hipLaunchKernelGGL(init_accs, dim3(1), dim3(64), 0, stream, accs);
    hipLaunchKernelGGL(convert_norm, dim3(3 * N / 4), dim3(256), 0, stream,
                       X, Y, Z, bmat, nscl);
    hipLaunchKernelGGL(gram_kernel, dim3(256, 6), dim3(256), 0, stream,
                       bmat, nscl, accs);
    hipLaunchKernelGGL(finalize_kernel, dim3(1), dim3(1), 0, stream, accs, out);
}